// Round 6
// baseline (140.155 us; speedup 1.0000x reference)
//
#include <hip/hip_runtime.h>
#include <hip/hip_bf16.h>
#include <stdint.h>

// ReplicatorDerivLayer on MI355X — factorized (no 2048x2048 Wm), 128^2 GEMM engine.
//  prep_x: x f32 -> xb bf16 [b][e][s] + xbT bf16 [b][s][e]
//  Wcat = [W1^T ; W2] bf16 [1024][512]
//  projcat: Fcat[s][0:512]=F1T[s,f], Fcat[s][512:1024]=F2T[s,f]
//  aux:  F2n[r][t] = fitnesses2 natural layout;  Sd[b][i] = masked diag Gram block
//  Gc[b][j][e,f] = sum_{t in blk j} xb[e,t] * F2n[f,t]   (K=256)
//  prefix: Gp[b][i-1] = sum_{j<i} Gc[b][j]  (bf16)
//  fitfused: fit[e, blk i] = Gp_i . F1T^T (K=512, i>0)  +  xb_blk . Sd^T (K=256)
//  finalize: avg = sum_s x*fit; out = relu(x*(1+fit-avg))
//
// GEMM engine: 128x128 tile, 4 waves, 32KB single-buffer LDS, 2-barrier K-loop
// (m97 structure: latency hidden by ~3 co-resident blocks/CU, not deep pipeline),
// XOR-swizzled LDS (inverse-swizzled global source + swizzled ds_read).

#define SEQ 2048
#define EMB 512
#define NBATCH 8

typedef unsigned short u16;
typedef __bf16 bf16x8 __attribute__((ext_vector_type(8)));
typedef float f32x4 __attribute__((ext_vector_type(4)));
typedef u16 u16x8 __attribute__((ext_vector_type(8)));

#define AS1 __attribute__((address_space(1)))
#define AS3 __attribute__((address_space(3)))

#define SBAR do { __builtin_amdgcn_sched_barrier(0); __builtin_amdgcn_s_barrier(); \
                  __builtin_amdgcn_sched_barrier(0); } while (0)
#define LGKM0 do { asm volatile("s_waitcnt lgkmcnt(0)" ::: "memory"); \
                   __builtin_amdgcn_sched_barrier(0); } while (0)

__device__ __forceinline__ u16 f2bf(float f) {
  uint32_t u = __builtin_bit_cast(uint32_t, f);
  uint32_t r = u + 0x7FFFu + ((u >> 16) & 1u);
  return (u16)(r >> 16);
}
__device__ __forceinline__ float bf2f(u16 u) {
  return __builtin_bit_cast(float, (uint32_t)u << 16);
}
__device__ __forceinline__ void gld_lds16(const void* g, void* l) {
  __builtin_amdgcn_global_load_lds((AS1 uint32_t*)g, (AS3 uint32_t*)l, 16, 0, 0);
}

// ---------------- prep_x ----------------
__global__ __launch_bounds__(256) void prep_x_kernel(const float* __restrict__ x,
    u16* __restrict__ xb, u16* __restrict__ xbT) {
  __shared__ float tile[64][65];
  const int b = blockIdx.z;
  const int s0 = blockIdx.x * 64, e0 = blockIdx.y * 64;
  const float* xin = x + (size_t)b * EMB * SEQ;
  const int tid = threadIdx.x;
  #pragma unroll
  for (int it = 0; it < 4; ++it) {
    int idx = it * 256 + tid;
    int r = idx >> 4, c4 = idx & 15;
    float4 v = *(const float4*)(xin + (size_t)(e0 + r) * SEQ + s0 + c4 * 4);
    tile[r][c4 * 4 + 0] = v.x; tile[r][c4 * 4 + 1] = v.y;
    tile[r][c4 * 4 + 2] = v.z; tile[r][c4 * 4 + 3] = v.w;
  }
  __syncthreads();
  u16* ob = xb + (size_t)b * EMB * SEQ;
  #pragma unroll
  for (int it = 0; it < 2; ++it) {
    int idx = it * 256 + tid; int r = idx >> 3, c8 = idx & 7;
    u16x8 o;
    #pragma unroll
    for (int q = 0; q < 8; ++q) o[q] = f2bf(tile[r][c8 * 8 + q]);
    *(u16x8*)(ob + (size_t)(e0 + r) * SEQ + s0 + c8 * 8) = o;
  }
  u16* obT = xbT + (size_t)b * SEQ * EMB;
  #pragma unroll
  for (int it = 0; it < 2; ++it) {
    int idx = it * 256 + tid; int r = idx >> 3, c8 = idx & 7;
    u16x8 o;
    #pragma unroll
    for (int q = 0; q < 8; ++q) o[q] = f2bf(tile[c8 * 8 + q][r]);
    *(u16x8*)(obT + (size_t)(s0 + r) * EMB + e0 + c8 * 8) = o;
  }
}

__global__ __launch_bounds__(256) void cast_bf16_kernel(const float* __restrict__ in,
                                                        u16* __restrict__ out, int n4) {
  int i = blockIdx.x * 256 + threadIdx.x;
  if (i >= n4) return;
  float4 v = reinterpret_cast<const float4*>(in)[i];
  ushort4 r;
  r.x = f2bf(v.x); r.y = f2bf(v.y); r.z = f2bf(v.z); r.w = f2bf(v.w);
  reinterpret_cast<ushort4*>(out)[i] = r;
}

__global__ __launch_bounds__(256) void transpose_cast_kernel(const float* __restrict__ in,
    u16* __restrict__ out, int R, int C) {
  __shared__ float tile[32][33];
  const int c0 = blockIdx.x * 32, r0 = blockIdx.y * 32;
  const int tx = threadIdx.x, ty = threadIdx.y;  // (32, 8)
  #pragma unroll
  for (int i = 0; i < 32; i += 8)
    tile[ty + i][tx] = in[(size_t)(r0 + ty + i) * C + c0 + tx];
  __syncthreads();
  #pragma unroll
  for (int i = 0; i < 32; i += 8)
    out[(size_t)(c0 + ty + i) * R + r0 + tx] = f2bf(tile[tx][ty + i]);
}

// ---------------- 128x128 single-buffer bt-GEMM engine ----------------
// C[m][n] += sum_k A[m][k]*B[n][k]; 4 waves in 2x2 grid, 64x64 per wave.
struct Smem128 {
  __align__(16) u16 LA[128 * 64];
  __align__(16) u16 LB[128 * 64];
};

__device__ __forceinline__ void gemm128(const u16* __restrict__ Ab, int ldA,
    const u16* __restrict__ Bb, int ldB, int nk, Smem128& sm, f32x4 (&acc)[4][4]) {
  const int tid = threadIdx.x, lane = tid & 63, wave = tid >> 6;
  const int wr = wave >> 1, wc = wave & 1;
  const int ar = lane & 15, asel = lane >> 4;

  // stage 128x64 bf16 (16KB): 1024 16B-chunks, 4/thread; LDS dest linear
  // (chunk L at byte L*16, wave-uniform base + lane*16); global source column
  // inverse-swizzled (cs = cc ^ (row&7)) to match swizzled ds_read below.
  auto stage = [&](const u16* g, int ld, int kcol, u16* lds) {
    #pragma unroll
    for (int it = 0; it < 4; ++it) {
      int L = it * 256 + tid;
      int row = L >> 3, cc = L & 7, cs = cc ^ (row & 7);
      gld_lds16(g + (size_t)row * ld + kcol + cs * 8,
                lds + (size_t)(it * 256 + wave * 64) * 8);
    }
  };
  auto ldfrag = [&](const u16* base, int rloc, int c2) -> bf16x8 {
    int cs = c2 ^ (rloc & 7);
    return *reinterpret_cast<const bf16x8*>(base + (size_t)(rloc * 8 + cs) * 8);
  };

  for (int t = 0; t < nk; ++t) {
    stage(Ab, ldA, t * 64, sm.LA);
    stage(Bb, ldB, t * 64, sm.LB);
    asm volatile("s_waitcnt vmcnt(0)" ::: "memory");
    SBAR;
    bf16x8 af[4][2], bf[4][2];
    #pragma unroll
    for (int m = 0; m < 4; ++m)
      #pragma unroll
      for (int kk = 0; kk < 2; ++kk)
        af[m][kk] = ldfrag(sm.LA, wr * 64 + m * 16 + ar, kk * 4 + asel);
    #pragma unroll
    for (int n = 0; n < 4; ++n)
      #pragma unroll
      for (int kk = 0; kk < 2; ++kk)
        bf[n][kk] = ldfrag(sm.LB, wc * 64 + n * 16 + ar, kk * 4 + asel);
    LGKM0;
    __builtin_amdgcn_s_setprio(1);
    #pragma unroll
    for (int m = 0; m < 4; ++m)
      #pragma unroll
      for (int n = 0; n < 4; ++n)
        #pragma unroll
        for (int kk = 0; kk < 2; ++kk)
          acc[m][n] = __builtin_amdgcn_mfma_f32_16x16x32_bf16(af[m][kk], bf[n][kk], acc[m][n], 0, 0, 0);
    __builtin_amdgcn_s_setprio(0);
    SBAR;  // all reads done (LGKM0 above) before next stage overwrites
  }
}

// ---------------- GEMM kernels (one template, 4 modes) ----------------
// MODE 0 projcat: grid (16,8,8):  Fcat = xbT . Wcat^T            (bf16 out)
// MODE 1 aux:     grid (96,1,8):  x<64 -> F2n = W2b . xbT^T;
//                                 x>=64 -> Sd sub-tiles (masked diag Gram)
// MODE 2 gc:      grid (16,1,64): Gc[b][j] = xb_blkj . F2n_blkj^T (bf16 out)
// MODE 3 fit:     grid (8,8,8):   fit[e,blk i] = Gp_i.F1T^T + xb_blk.Sd^T (f32 out)
template<int MODE>
__global__ __launch_bounds__(256, 3) void k_gemm(
    const u16* __restrict__ X1, const u16* __restrict__ X2,
    const u16* __restrict__ X3, const u16* __restrict__ X4,
    u16* __restrict__ O16, u16* __restrict__ O16b, float* __restrict__ O32) {
  __shared__ Smem128 sm;
  const int tid  = threadIdx.x;
  const int lane = tid & 63;
  const int wave = tid >> 6;
  const int wr = wave >> 1;
  const int wc = wave & 1;
  const int bz = blockIdx.z;

  f32x4 acc[4][4];
  #pragma unroll
  for (int i = 0; i < 4; ++i)
    #pragma unroll
    for (int j = 0; j < 4; ++j) acc[i][j] = (f32x4){0.f, 0.f, 0.f, 0.f};

  const int r0 = (lane >> 4) * 4;
  const int cn = lane & 15;

  if (MODE == 0) {
    const int m = blockIdx.x, n = blockIdx.y;
    const u16* A = X1 + (size_t)bz * SEQ * EMB + (size_t)(m * 128) * 512;
    const u16* B = X2 + (size_t)(n * 128) * 512;
    gemm128(A, 512, B, 512, 8, sm, acc);
    u16* C = O16 + (size_t)bz * SEQ * 1024;
    #pragma unroll
    for (int mm = 0; mm < 4; ++mm)
      #pragma unroll
      for (int nn = 0; nn < 4; ++nn)
        #pragma unroll
        for (int r = 0; r < 4; ++r) {
          int lr = wr * 64 + mm * 16 + r0 + r, lc = wc * 64 + nn * 16 + cn;
          C[(size_t)(m * 128 + lr) * 1024 + n * 128 + lc] = f2bf(acc[mm][nn][r]);
        }
  } else if (MODE == 1) {
    const int xx = blockIdx.x;
    if (xx < 64) {
      // F2n[r][t] = sum_f W2b[r,f] * xbT[t,f]
      const int m2 = xx >> 4, n2 = xx & 15;
      const u16* A = X1 + (size_t)(m2 * 128) * 512;
      const u16* B = X2 + (size_t)bz * SEQ * EMB + (size_t)(n2 * 128) * 512;
      gemm128(A, 512, B, 512, 8, sm, acc);
      u16* C = O16 + (size_t)bz * EMB * SEQ;
      #pragma unroll
      for (int mm = 0; mm < 4; ++mm)
        #pragma unroll
        for (int nn = 0; nn < 4; ++nn)
          #pragma unroll
          for (int r = 0; r < 4; ++r) {
            int lr = wr * 64 + mm * 16 + r0 + r, lc = wc * 64 + nn * 16 + cn;
            C[(size_t)(m2 * 128 + lr) * SEQ + n2 * 128 + lc] = f2bf(acc[mm][nn][r]);
          }
    } else {
      // Sd[b][i] sub-tile (p,q): rows p*128.., cols q*128.. of the 256x256 diag block
      const int idx = xx - 64;
      const int i = idx >> 2, p = (idx >> 1) & 1, q = idx & 1;
      u16* C = O16b + (size_t)(bz * 8 + i) * 256 * 256;
      if (p == 0 && q == 1) {
        // strictly-upper sub-tile: all zeros, skip the GEMM
        u16x8 z = {0, 0, 0, 0, 0, 0, 0, 0};
        #pragma unroll
        for (int it = 0; it < 8; ++it) {
          int id2 = it * 256 + tid;
          int r = id2 >> 4, c8 = id2 & 15;
          *(u16x8*)(C + (size_t)r * 256 + 128 + c8 * 8) = z;
        }
        return;
      }
      const u16* Fb = X3 + (size_t)bz * SEQ * 1024;
      const u16* A = Fb + (size_t)(i * 256 + p * 128) * 1024;
      const u16* B = Fb + 512 + (size_t)(i * 256 + q * 128) * 1024;
      gemm128(A, 1024, B, 1024, 8, sm, acc);
      #pragma unroll
      for (int mm = 0; mm < 4; ++mm)
        #pragma unroll
        for (int nn = 0; nn < 4; ++nn)
          #pragma unroll
          for (int r = 0; r < 4; ++r) {
            int lr = wr * 64 + mm * 16 + r0 + r, lc = wc * 64 + nn * 16 + cn;
            int grow = p * 128 + lr, gcol = q * 128 + lc;
            float v = (gcol > grow) ? 0.f : acc[mm][nn][r];  // keep t <= s
            C[(size_t)grow * 256 + gcol] = f2bf(v);
          }
    }
  } else if (MODE == 2) {
    // Gc[b][j][e,f] = sum_{t in blk j} xb[e,t] * F2n[f,t]
    const int m = blockIdx.x >> 2, n = blockIdx.x & 3;
    const int b = bz >> 3, j = bz & 7;
    const u16* A = X1 + (size_t)b * EMB * SEQ + (size_t)(m * 128) * SEQ + j * 256;
    const u16* B = X2 + (size_t)b * EMB * SEQ + (size_t)(n * 128) * SEQ + j * 256;
    gemm128(A, SEQ, B, SEQ, 4, sm, acc);
    u16* C = O16 + (size_t)(b * 8 + j) * EMB * EMB;
    #pragma unroll
    for (int mm = 0; mm < 4; ++mm)
      #pragma unroll
      for (int nn = 0; nn < 4; ++nn)
        #pragma unroll
        for (int r = 0; r < 4; ++r) {
          int lr = wr * 64 + mm * 16 + r0 + r, lc = wc * 64 + nn * 16 + cn;
          C[(size_t)(m * 128 + lr) * EMB + n * 128 + lc] = f2bf(acc[mm][nn][r]);
        }
  } else {
    // fitfused: (m e-tile 0..3, n 0..1, i = blockIdx.y, b = bz)
    const int m = blockIdx.x >> 1, n = blockIdx.x & 1, i = blockIdx.y;
    if (i > 0) {
      const u16* A = X1 + (size_t)(bz * 7 + i - 1) * EMB * EMB + (size_t)(m * 128) * 512;
      const u16* B = X2 + (size_t)bz * SEQ * 1024 + (size_t)(i * 256 + n * 128) * 1024;
      gemm128(A, 512, B, 1024, 8, sm, acc);
    }
    {
      const u16* A = X3 + (size_t)bz * EMB * SEQ + (size_t)(m * 128) * SEQ + i * 256;
      const u16* B = X4 + (size_t)(bz * 8 + i) * 256 * 256 + (size_t)(n * 128) * 256;
      gemm128(A, SEQ, B, 256, 4, sm, acc);
    }
    float* C = O32 + (size_t)bz * EMB * SEQ;
    #pragma unroll
    for (int mm = 0; mm < 4; ++mm)
      #pragma unroll
      for (int nn = 0; nn < 4; ++nn)
        #pragma unroll
        for (int r = 0; r < 4; ++r) {
          int lr = wr * 64 + mm * 16 + r0 + r, lc = wc * 64 + nn * 16 + cn;
          C[(size_t)(m * 128 + lr) * SEQ + i * 256 + n * 128 + lc] = acc[mm][nn][r];
        }
  }
}

// ---------------- prefix over chunks: Gp[b][i-1] = sum_{j<i} Gc[b][j] ----------------
__global__ __launch_bounds__(256) void k_prefix(const u16* __restrict__ Gc,
                                                u16* __restrict__ Gp) {
  const int b = blockIdx.z;
  const size_t base = ((size_t)blockIdx.x * 256 + threadIdx.x) * 8;
  float run[8] = {0.f, 0.f, 0.f, 0.f, 0.f, 0.f, 0.f, 0.f};
  #pragma unroll
  for (int j = 0; j < 7; ++j) {
    u16x8 v = *(const u16x8*)(Gc + (size_t)(b * 8 + j) * EMB * EMB + base);
    u16x8 o;
    #pragma unroll
    for (int q = 0; q < 8; ++q) { run[q] += bf2f(v[q]); o[q] = f2bf(run[q]); }
    *(u16x8*)(Gp + (size_t)(b * 7 + j) * EMB * EMB + base) = o;
  }
}

// ---------------- finalize ----------------
__global__ __launch_bounds__(256) void finalize_kernel(const u16* __restrict__ xb,
    const float* __restrict__ fit, float* __restrict__ out) {
  const size_t row = blockIdx.x;  // b*EMB + e
  const u16* xr = xb + row * SEQ;
  const float* fr = fit + row * SEQ;
  float* orow = out + row * SEQ;
  const int tid = threadIdx.x;

  float xv[2][4]; float4 fv[2];
  float part = 0.f;
  #pragma unroll
  for (int i = 0; i < 2; ++i) {
    const int s0 = i * 1024 + tid * 4;
    ushort4 xu = *reinterpret_cast<const ushort4*>(xr + s0);
    xv[i][0] = bf2f(xu.x); xv[i][1] = bf2f(xu.y); xv[i][2] = bf2f(xu.z); xv[i][3] = bf2f(xu.w);
    fv[i] = reinterpret_cast<const float4*>(fr)[i * 256 + tid];
    part += xv[i][0] * fv[i].x + xv[i][1] * fv[i].y + xv[i][2] * fv[i].z + xv[i][3] * fv[i].w;
  }
  #pragma unroll
  for (int off = 1; off < 64; off <<= 1) part += __shfl_xor(part, off);
  __shared__ float wsum[4];
  const int wave = tid >> 6, lane = tid & 63;
  if (lane == 0) wsum[wave] = part;
  __syncthreads();
  const float avg = wsum[0] + wsum[1] + wsum[2] + wsum[3];

  #pragma unroll
  for (int i = 0; i < 2; ++i) {
    float4 o;
    o.x = xv[i][0] * (1.f + fv[i].x - avg); o.x = o.x > 0.f ? o.x : 0.f;
    o.y = xv[i][1] * (1.f + fv[i].y - avg); o.y = o.y > 0.f ? o.y : 0.f;
    o.z = xv[i][2] * (1.f + fv[i].z - avg); o.z = o.z > 0.f ? o.z : 0.f;
    o.w = xv[i][3] * (1.f + fv[i].w - avg); o.w = o.w > 0.f ? o.w : 0.f;
    reinterpret_cast<float4*>(orow)[i * 256 + tid] = o;
  }
}

extern "C" void kernel_launch(void* const* d_in, const int* in_sizes, int n_in,
                              void* d_out, int out_size, void* d_ws, size_t ws_size,
                              hipStream_t stream) {
  const float* x  = (const float*)d_in[0];
  const float* W1 = (const float*)d_in[1];
  const float* W2 = (const float*)d_in[2];
  float* out = (float*)d_out;

  char* ws = (char*)d_ws;
  const size_t nX = (size_t)NBATCH * EMB * SEQ;  // 8,388,608

  size_t off = 0;
  u16* xb   = (u16*)(ws + off); off += nX * 2;                          // 16 MB
  u16* Fcat = (u16*)(ws + off); off += (size_t)NBATCH * SEQ * 1024 * 2; // 32 MB
  const size_t offOverlay = off;                                        // fit overlays next 33 MB
  u16* xbT  = (u16*)(ws + off); off += nX * 2;                          // 16 MB (dead after aux)
  u16* Wcat = (u16*)(ws + off); off += (size_t)1024 * 512 * 2;          // 1 MB  (dead after aux)
  u16* F2n  = (u16*)(ws + off); off += nX * 2;                          // 16 MB (dead after Gc)
  u16* Sd   = (u16*)(ws + off); off += (size_t)NBATCH * 8 * 256 * 256 * 2;  // 8 MB
  u16* Gc   = (u16*)(ws + off); off += (size_t)NBATCH * 8 * EMB * EMB * 2;  // 32 MB
  u16* Gp   = (u16*)(ws + off); off += (size_t)NBATCH * 7 * EMB * EMB * 2;  // 28 MB
  float* fit = (float*)(ws + offOverlay);                               // 32 MB
  // total: ~149 MiB

  // 1) prep
  prep_x_kernel<<<dim3(SEQ / 64, EMB / 64, NBATCH), 256, 0, stream>>>(x, xb, xbT);
  transpose_cast_kernel<<<dim3(EMB / 32, EMB / 32), dim3(32, 8), 0, stream>>>(W1, Wcat, EMB, EMB);
  cast_bf16_kernel<<<EMB * EMB / 4 / 256, 256, 0, stream>>>(W2, Wcat + (size_t)512 * 512, EMB * EMB / 4);

  // 2) projcat: Fcat[s][n] = sum_k xbT[s][k] Wcat[n][k]
  k_gemm<0><<<dim3(16, 8, NBATCH), 256, 0, stream>>>(
      xbT, Wcat, nullptr, nullptr, Fcat, nullptr, nullptr);

  // 3) aux: F2n (natural-layout 2nd projection) + Sd (masked diag Gram blocks)
  k_gemm<1><<<dim3(96, 1, NBATCH), 256, 0, stream>>>(
      Wcat + (size_t)512 * 512, xbT, Fcat, nullptr, F2n, Sd, nullptr);

  // 4) Gc[b][j] = xb_blkj . F2n_blkj^T  (K=256 per chunk)
  k_gemm<2><<<dim3(16, 1, 64), 256, 0, stream>>>(
      xb, F2n, nullptr, nullptr, Gc, nullptr, nullptr);

  // 5) prefix-sum chunks -> Gp
  k_prefix<<<dim3(128, 1, NBATCH), 256, 0, stream>>>(Gc, Gp);

  // 6) fitfused: fit = Gp_i . F1T^T + xb_blk . Sd^T
  k_gemm<3><<<dim3(8, 8, NBATCH), 256, 0, stream>>>(
      Gp, Fcat, xb, Sd, nullptr, nullptr, fit);

  // 7) finalize
  finalize_kernel<<<NBATCH * EMB, 256, 0, stream>>>(xb, fit, out);
}

// Round 7
// 135.405 us; speedup vs baseline: 1.0351x; 1.0351x over previous
//
#include <hip/hip_runtime.h>
#include <hip/hip_bf16.h>
#include <stdint.h>

// ReplicatorDerivLayer on MI355X — factorized causal pipeline, 256^2 4-phase engine.
//  prep_x: x f32 -> xb bf16 [b][e][s] + xbT bf16 [b][s][e]
//  prep_w: Wcat = [W1^T ; W2] bf16 [1024][512]
//  D1 projcat+F2n: Fcat[s][0:512]=F1T, Fcat[s][512:1024]=F2T; F2n[r][t] (natural layout)
//  D2 Sd+Gc: Sd[b][i] = masked 256^2 diag Gram; Gc[b][j][e,f] = xb_blkj . F2n_blkj^T
//  D3 prefix: Gp[b][i-1] = sum_{j<i} Gc[b][j]
//  D4 fitfused (single 12-tile pipe): fitb[e, blk i] = Gp_i.F1T^T + xb_blk.Sd^T (bf16)
//  D5 finalize: avg = sum_s x*fit; out = relu(x*(1+fit-avg))
// Engine: 256x256, 8 waves, dbuf LDS 128KB, XOR-swizzle, counted vmcnt(4).

#define SEQ 2048
#define EMB 512
#define NBATCH 8

typedef unsigned short u16;
typedef __bf16 bf16x8 __attribute__((ext_vector_type(8)));
typedef float f32x4 __attribute__((ext_vector_type(4)));
typedef u16 u16x8 __attribute__((ext_vector_type(8)));

#define AS1 __attribute__((address_space(1)))
#define AS3 __attribute__((address_space(3)))

#define SBAR do { __builtin_amdgcn_sched_barrier(0); __builtin_amdgcn_s_barrier(); \
                  __builtin_amdgcn_sched_barrier(0); } while (0)
#define LGKM0 do { asm volatile("s_waitcnt lgkmcnt(0)" ::: "memory"); \
                   __builtin_amdgcn_sched_barrier(0); } while (0)

__device__ __forceinline__ u16 f2bf(float f) {
  uint32_t u = __builtin_bit_cast(uint32_t, f);
  uint32_t r = u + 0x7FFFu + ((u >> 16) & 1u);
  return (u16)(r >> 16);
}
__device__ __forceinline__ float bf2f(u16 u) {
  return __builtin_bit_cast(float, (uint32_t)u << 16);
}
__device__ __forceinline__ void gld_lds16(const void* g, void* l) {
  __builtin_amdgcn_global_load_lds((AS1 uint32_t*)g, (AS3 uint32_t*)l, 16, 0, 0);
}

// ---------------- prep_x ----------------
__global__ __launch_bounds__(256) void prep_x_kernel(const float* __restrict__ x,
    u16* __restrict__ xb, u16* __restrict__ xbT) {
  __shared__ float tile[64][65];
  const int b = blockIdx.z;
  const int s0 = blockIdx.x * 64, e0 = blockIdx.y * 64;
  const float* xin = x + (size_t)b * EMB * SEQ;
  const int tid = threadIdx.x;
  #pragma unroll
  for (int it = 0; it < 4; ++it) {
    int idx = it * 256 + tid;
    int r = idx >> 4, c4 = idx & 15;
    float4 v = *(const float4*)(xin + (size_t)(e0 + r) * SEQ + s0 + c4 * 4);
    tile[r][c4 * 4 + 0] = v.x; tile[r][c4 * 4 + 1] = v.y;
    tile[r][c4 * 4 + 2] = v.z; tile[r][c4 * 4 + 3] = v.w;
  }
  __syncthreads();
  u16* ob = xb + (size_t)b * EMB * SEQ;
  #pragma unroll
  for (int it = 0; it < 2; ++it) {
    int idx = it * 256 + tid; int r = idx >> 3, c8 = idx & 7;
    u16x8 o;
    #pragma unroll
    for (int q = 0; q < 8; ++q) o[q] = f2bf(tile[r][c8 * 8 + q]);
    *(u16x8*)(ob + (size_t)(e0 + r) * SEQ + s0 + c8 * 8) = o;
  }
  u16* obT = xbT + (size_t)b * SEQ * EMB;
  #pragma unroll
  for (int it = 0; it < 2; ++it) {
    int idx = it * 256 + tid; int r = idx >> 3, c8 = idx & 7;
    u16x8 o;
    #pragma unroll
    for (int q = 0; q < 8; ++q) o[q] = f2bf(tile[c8 * 8 + q][r]);
    *(u16x8*)(obT + (size_t)(s0 + r) * EMB + e0 + c8 * 8) = o;
  }
}

// ---------------- prep_w: Wcat = [W1^T ; W2] ----------------
__global__ __launch_bounds__(256) void prep_w_kernel(const float* __restrict__ W1,
    const float* __restrict__ W2, u16* __restrict__ Wcat) {
  __shared__ float tile[32][33];
  const int c0 = blockIdx.x * 32, r0 = blockIdx.y * 32;
  const int tx = threadIdx.x, ty = threadIdx.y;  // (32, 8)
  if (blockIdx.z == 0) {
    #pragma unroll
    for (int i = 0; i < 32; i += 8)
      tile[ty + i][tx] = W1[(size_t)(r0 + ty + i) * EMB + c0 + tx];
    __syncthreads();
    #pragma unroll
    for (int i = 0; i < 32; i += 8)
      Wcat[(size_t)(c0 + ty + i) * EMB + r0 + tx] = f2bf(tile[tx][ty + i]);
  } else {
    u16* W2b = Wcat + (size_t)512 * 512;
    #pragma unroll
    for (int i = 0; i < 32; i += 8)
      W2b[(size_t)(r0 + ty + i) * EMB + c0 + tx] =
          f2bf(W2[(size_t)(r0 + ty + i) * EMB + c0 + tx]);
  }
}

// ---------------- the 256x256 4-phase pipelined engine ----------------
struct Smem {
  __align__(16) u16 LA[2][256 * 64];
  __align__(16) u16 LB[2][256 * 64];
};

// par(t, ab, g, ld, k): operand source for K-tile t, ab=0->A, 1->B.
template<typename PAR>
__device__ __forceinline__ void gemm_pipe(PAR par, int nk, Smem& sm, f32x4 (&acc)[8][4]) {
  const int tid  = threadIdx.x;
  const int lane = tid & 63;
  const int wave = tid >> 6;
  const int wr = wave >> 2;
  const int wc = wave & 3;

  auto stage_half = [&](int t, int ab, int half, u16* lds) {
    const u16* g; int ld, k;
    par(t, ab, g, ld, k);
    #pragma unroll
    for (int p = 0; p < 2; ++p) {
      int c = p * 512 + tid;              // chunk 0..1023
      int row = c >> 3, cc = c & 7;
      int cs = cc ^ (row & 7);
      gld_lds16(g + (size_t)(half * 128 + row) * ld + k + cs * 8,
                lds + (size_t)(p * 512 + wave * 64) * 8);
    }
  };
  auto ldfrag = [&](const u16* base, int rloc, int c2) -> bf16x8 {
    int cs = c2 ^ (rloc & 7);
    return *reinterpret_cast<const bf16x8*>(base + (size_t)(rloc * 8 + cs) * 8);
  };

  // prologue stage order (vmcnt counting depends on it): 0.A0,0.A1,0.B0,0.B1,[1.B0,1.B1]
  stage_half(0, 0, 0, sm.LA[0]);
  stage_half(0, 0, 1, sm.LA[0] + 8192);
  stage_half(0, 1, 0, sm.LB[0]);
  stage_half(0, 1, 1, sm.LB[0] + 8192);
  if (nk > 1) {
    stage_half(1, 1, 0, sm.LB[1]);
    stage_half(1, 1, 1, sm.LB[1] + 8192);
  }
  if (nk > 1) { asm volatile("s_waitcnt vmcnt(4)" ::: "memory"); }
  else        { asm volatile("s_waitcnt vmcnt(0)" ::: "memory"); }
  SBAR;

  const int ar = lane & 15;
  const int asel = lane >> 4;
  bf16x8 af[4][2], bf0[2][2], bf1[2][2];

  for (int t = 0; t < nk; ++t) {
    const int sel = t & 1;
    const u16* a_ = sm.LA[sel];
    const u16* b_ = sm.LB[sel];

    // P1: read A[m0-3], B[n0-1]; stage (t+1).A-h0; MFMA mA x nA
    #pragma unroll
    for (int m = 0; m < 4; ++m)
      #pragma unroll
      for (int kk = 0; kk < 2; ++kk)
        af[m][kk] = ldfrag(a_, wr * 128 + m * 16 + ar, kk * 4 + asel);
    #pragma unroll
    for (int n = 0; n < 2; ++n)
      #pragma unroll
      for (int kk = 0; kk < 2; ++kk)
        bf0[n][kk] = ldfrag(b_, wc * 64 + n * 16 + ar, kk * 4 + asel);
    if (t + 1 < nk) stage_half(t + 1, 0, 0, sm.LA[sel ^ 1]);
    SBAR; LGKM0;
    __builtin_amdgcn_s_setprio(1);
    #pragma unroll
    for (int m = 0; m < 4; ++m)
      #pragma unroll
      for (int n = 0; n < 2; ++n)
        #pragma unroll
        for (int kk = 0; kk < 2; ++kk)
          acc[m][n] = __builtin_amdgcn_mfma_f32_16x16x32_bf16(af[m][kk], bf0[n][kk], acc[m][n], 0, 0, 0);
    __builtin_amdgcn_s_setprio(0);
    SBAR;

    // P2: read B[n2-3]; stage (t+1).A-h1; MFMA mA x nB
    #pragma unroll
    for (int n = 0; n < 2; ++n)
      #pragma unroll
      for (int kk = 0; kk < 2; ++kk)
        bf1[n][kk] = ldfrag(b_, wc * 64 + (n + 2) * 16 + ar, kk * 4 + asel);
    if (t + 1 < nk) stage_half(t + 1, 0, 1, sm.LA[sel ^ 1] + 8192);
    SBAR; LGKM0;
    __builtin_amdgcn_s_setprio(1);
    #pragma unroll
    for (int m = 0; m < 4; ++m)
      #pragma unroll
      for (int n = 0; n < 2; ++n)
        #pragma unroll
        for (int kk = 0; kk < 2; ++kk)
          acc[m][n + 2] = __builtin_amdgcn_mfma_f32_16x16x32_bf16(af[m][kk], bf1[n][kk], acc[m][n + 2], 0, 0, 0);
    __builtin_amdgcn_s_setprio(0);
    SBAR;

    // P3: read A[m4-7]; stage (t+2).B-h0; MFMA mB x nB
    #pragma unroll
    for (int m = 0; m < 4; ++m)
      #pragma unroll
      for (int kk = 0; kk < 2; ++kk)
        af[m][kk] = ldfrag(a_, wr * 128 + 64 + m * 16 + ar, kk * 4 + asel);
    if (t + 2 < nk) stage_half(t + 2, 1, 0, sm.LB[sel]);
    SBAR; LGKM0;
    __builtin_amdgcn_s_setprio(1);
    #pragma unroll
    for (int m = 0; m < 4; ++m)
      #pragma unroll
      for (int n = 0; n < 2; ++n)
        #pragma unroll
        for (int kk = 0; kk < 2; ++kk)
          acc[m + 4][n + 2] = __builtin_amdgcn_mfma_f32_16x16x32_bf16(af[m][kk], bf1[n][kk], acc[m + 4][n + 2], 0, 0, 0);
    __builtin_amdgcn_s_setprio(0);
    SBAR;

    // P4: stage (t+2).B-h1; MFMA mB x nA; counted vmcnt for next tile
    if (t + 2 < nk) stage_half(t + 2, 1, 1, sm.LB[sel] + 8192);
    SBAR;
    __builtin_amdgcn_s_setprio(1);
    #pragma unroll
    for (int m = 0; m < 4; ++m)
      #pragma unroll
      for (int n = 0; n < 2; ++n)
        #pragma unroll
        for (int kk = 0; kk < 2; ++kk)
          acc[m + 4][n] = __builtin_amdgcn_mfma_f32_16x16x32_bf16(af[m][kk], bf0[n][kk], acc[m + 4][n], 0, 0, 0);
    __builtin_amdgcn_s_setprio(0);
    if (t + 1 < nk) {
      if (t + 2 < nk) { asm volatile("s_waitcnt vmcnt(4)" ::: "memory"); }
      else            { asm volatile("s_waitcnt vmcnt(0)" ::: "memory"); }
    }
    SBAR;
  }
}

// ---------------- GEMM kernels ----------------
// MODE 0 grid (48,1,8): x<32 -> Fcat tile (m=x>>2,n=x&3); x>=32 -> F2n (m2,n2)
// MODE 1 grid (40,1,8): x<8 -> Sd[i=x] masked diag; x>=8 -> Gc (j,m,n)
// MODE 2 grid (16,1,8): fitb[e blk m][s blk i] single 12-tile pipe (i=x>>1,m=x&1)
template<int MODE>
__global__ __launch_bounds__(512, 2) void k_gemm(
    const u16* __restrict__ X1, const u16* __restrict__ X2,
    const u16* __restrict__ X3, const u16* __restrict__ X4,
    u16* __restrict__ O16, u16* __restrict__ O16b) {
  __shared__ Smem sm;
  const int tid  = threadIdx.x;
  const int lane = tid & 63;
  const int wave = tid >> 6;
  const int wr = wave >> 2;
  const int wc = wave & 3;
  const int bz = blockIdx.z;

  f32x4 acc[8][4];
  #pragma unroll
  for (int i = 0; i < 8; ++i)
    #pragma unroll
    for (int j = 0; j < 4; ++j) acc[i][j] = (f32x4){0.f, 0.f, 0.f, 0.f};

  const int r0 = (lane >> 4) * 4;
  const int cn = lane & 15;

  if (MODE == 0) {
    const int xx = blockIdx.x;
    const u16* Ap; const u16* Bp;
    if (xx < 32) {
      const int m = xx >> 2, n = xx & 3;
      Ap = X1 + (size_t)bz * SEQ * EMB + (size_t)(m * 256) * 512;   // xbT rows s
      Bp = X2 + (size_t)(n * 256) * 512;                            // Wcat rows n
      auto par = [&](int t, int ab, const u16*& g, int& ld, int& k) {
        g = ab ? Bp : Ap; ld = 512; k = t * 64;
      };
      gemm_pipe(par, 8, sm, acc);
      u16* C = O16 + (size_t)bz * SEQ * 1024;
      #pragma unroll
      for (int mm = 0; mm < 8; ++mm)
        #pragma unroll
        for (int nn = 0; nn < 4; ++nn)
          #pragma unroll
          for (int r = 0; r < 4; ++r) {
            int lr = wr * 128 + mm * 16 + r0 + r, lc = wc * 64 + nn * 16 + cn;
            C[(size_t)(m * 256 + lr) * 1024 + n * 256 + lc] = f2bf(acc[mm][nn][r]);
          }
    } else {
      const int m2 = (xx - 32) >> 3, n2 = (xx - 32) & 7;
      Ap = X2 + (size_t)512 * 512 + (size_t)(m2 * 256) * 512;       // W2b rows r
      Bp = X1 + (size_t)bz * SEQ * EMB + (size_t)(n2 * 256) * 512;  // xbT rows t
      auto par = [&](int t, int ab, const u16*& g, int& ld, int& k) {
        g = ab ? Bp : Ap; ld = 512; k = t * 64;
      };
      gemm_pipe(par, 8, sm, acc);
      u16* C = O16b + (size_t)bz * EMB * SEQ;
      #pragma unroll
      for (int mm = 0; mm < 8; ++mm)
        #pragma unroll
        for (int nn = 0; nn < 4; ++nn)
          #pragma unroll
          for (int r = 0; r < 4; ++r) {
            int lr = wr * 128 + mm * 16 + r0 + r, lc = wc * 64 + nn * 16 + cn;
            C[(size_t)(m2 * 256 + lr) * SEQ + n2 * 256 + lc] = f2bf(acc[mm][nn][r]);
          }
    }
  } else if (MODE == 1) {
    const int xx = blockIdx.x;
    if (xx < 8) {
      const int i = xx;
      const u16* Fb = X1 + (size_t)bz * SEQ * 1024;
      const u16* Ap = Fb + (size_t)(i * 256) * 1024;        // F1T rows s
      const u16* Bp = Fb + 512 + (size_t)(i * 256) * 1024;  // F2T rows t
      auto par = [&](int t, int ab, const u16*& g, int& ld, int& k) {
        g = ab ? Bp : Ap; ld = 1024; k = t * 64;
      };
      gemm_pipe(par, 8, sm, acc);
      u16* C = O16 + (size_t)(bz * 8 + i) * 256 * 256;
      #pragma unroll
      for (int mm = 0; mm < 8; ++mm)
        #pragma unroll
        for (int nn = 0; nn < 4; ++nn)
          #pragma unroll
          for (int r = 0; r < 4; ++r) {
            int lr = wr * 128 + mm * 16 + r0 + r, lc = wc * 64 + nn * 16 + cn;
            float v = (lc > lr) ? 0.f : acc[mm][nn][r];  // keep t <= s
            C[(size_t)lr * 256 + lc] = f2bf(v);
          }
    } else {
      const int y = xx - 8;
      const int j = y >> 2, m = (y >> 1) & 1, n = y & 1;
      const u16* Ap = X2 + (size_t)bz * EMB * SEQ + (size_t)(m * 256) * SEQ + j * 256; // xb rows e
      const u16* Bp = X3 + (size_t)bz * EMB * SEQ + (size_t)(n * 256) * SEQ + j * 256; // F2n rows f
      auto par = [&](int t, int ab, const u16*& g, int& ld, int& k) {
        g = ab ? Bp : Ap; ld = SEQ; k = t * 64;
      };
      gemm_pipe(par, 4, sm, acc);
      u16* C = O16b + (size_t)(bz * 8 + j) * EMB * EMB;
      #pragma unroll
      for (int mm = 0; mm < 8; ++mm)
        #pragma unroll
        for (int nn = 0; nn < 4; ++nn)
          #pragma unroll
          for (int r = 0; r < 4; ++r) {
            int lr = wr * 128 + mm * 16 + r0 + r, lc = wc * 64 + nn * 16 + cn;
            C[(size_t)(m * 256 + lr) * EMB + n * 256 + lc] = f2bf(acc[mm][nn][r]);
          }
    }
  } else {
    // fitfused: i = s-block, m = e-half; tiles 0-7: Gp_i.F1T^T; 8-11: xb_blk.Sd^T
    const int i = blockIdx.x >> 1, m = blockIdx.x & 1;
    const u16* Agp = (i > 0) ? X1 + (size_t)(bz * 7 + i - 1) * EMB * EMB + (size_t)(m * 256) * 512
                             : X1;
    const u16* Bf1 = X2 + (size_t)bz * SEQ * 1024 + (size_t)(i * 256) * 1024;
    const u16* Axb = X3 + (size_t)bz * EMB * SEQ + (size_t)(m * 256) * SEQ;
    const u16* Bsd = X4 + (size_t)(bz * 8 + i) * 256 * 256;
    auto par = [&](int t, int ab, const u16*& g, int& ld, int& k) {
      int tt = (i > 0) ? t : t + 8;
      if (tt < 8) {
        if (!ab) { g = Agp; ld = 512;  k = tt * 64; }
        else     { g = Bf1; ld = 1024; k = tt * 64; }
      } else {
        int u = tt - 8;
        if (!ab) { g = Axb; ld = SEQ; k = i * 256 + u * 64; }
        else     { g = Bsd; ld = 256; k = u * 64; }
      }
    };
    gemm_pipe(par, (i > 0) ? 12 : 4, sm, acc);
    u16* C = O16 + (size_t)bz * EMB * SEQ;
    #pragma unroll
    for (int mm = 0; mm < 8; ++mm)
      #pragma unroll
      for (int nn = 0; nn < 4; ++nn)
        #pragma unroll
        for (int r = 0; r < 4; ++r) {
          int lr = wr * 128 + mm * 16 + r0 + r, lc = wc * 64 + nn * 16 + cn;
          C[(size_t)(m * 256 + lr) * SEQ + i * 256 + lc] = f2bf(acc[mm][nn][r]);
        }
  }
}

// ---------------- prefix over chunks: Gp[b][i-1] = sum_{j<i} Gc[b][j] ----------------
__global__ __launch_bounds__(256) void k_prefix(const u16* __restrict__ Gc,
                                                u16* __restrict__ Gp) {
  const int b = blockIdx.z;
  const size_t base = ((size_t)blockIdx.x * 256 + threadIdx.x) * 8;
  float run[8] = {0.f, 0.f, 0.f, 0.f, 0.f, 0.f, 0.f, 0.f};
  #pragma unroll
  for (int j = 0; j < 7; ++j) {
    u16x8 v = *(const u16x8*)(Gc + (size_t)(b * 8 + j) * EMB * EMB + base);
    u16x8 o;
    #pragma unroll
    for (int q = 0; q < 8; ++q) { run[q] += bf2f(v[q]); o[q] = f2bf(run[q]); }
    *(u16x8*)(Gp + (size_t)(b * 7 + j) * EMB * EMB + base) = o;
  }
}

// ---------------- finalize (fit in bf16) ----------------
__global__ __launch_bounds__(256) void finalize_kernel(const u16* __restrict__ xb,
    const u16* __restrict__ fitb, float* __restrict__ out) {
  const size_t row = blockIdx.x;  // b*EMB + e
  const u16* xr = xb + row * SEQ;
  const u16* fr = fitb + row * SEQ;
  float* orow = out + row * SEQ;
  const int tid = threadIdx.x;

  float xv[2][4], fv[2][4];
  float part = 0.f;
  #pragma unroll
  for (int i = 0; i < 2; ++i) {
    const int s0 = i * 1024 + tid * 4;
    ushort4 xu = *reinterpret_cast<const ushort4*>(xr + s0);
    ushort4 fu = *reinterpret_cast<const ushort4*>(fr + s0);
    xv[i][0] = bf2f(xu.x); xv[i][1] = bf2f(xu.y); xv[i][2] = bf2f(xu.z); xv[i][3] = bf2f(xu.w);
    fv[i][0] = bf2f(fu.x); fv[i][1] = bf2f(fu.y); fv[i][2] = bf2f(fu.z); fv[i][3] = bf2f(fu.w);
    part += xv[i][0] * fv[i][0] + xv[i][1] * fv[i][1] + xv[i][2] * fv[i][2] + xv[i][3] * fv[i][3];
  }
  #pragma unroll
  for (int off = 1; off < 64; off <<= 1) part += __shfl_xor(part, off);
  __shared__ float wsum[4];
  const int wave = tid >> 6, lane = tid & 63;
  if (lane == 0) wsum[wave] = part;
  __syncthreads();
  const float avg = wsum[0] + wsum[1] + wsum[2] + wsum[3];

  #pragma unroll
  for (int i = 0; i < 2; ++i) {
    float4 o;
    o.x = xv[i][0] * (1.f + fv[i][0] - avg); o.x = o.x > 0.f ? o.x : 0.f;
    o.y = xv[i][1] * (1.f + fv[i][1] - avg); o.y = o.y > 0.f ? o.y : 0.f;
    o.z = xv[i][2] * (1.f + fv[i][2] - avg); o.z = o.z > 0.f ? o.z : 0.f;
    o.w = xv[i][3] * (1.f + fv[i][3] - avg); o.w = o.w > 0.f ? o.w : 0.f;
    reinterpret_cast<float4*>(orow)[i * 256 + tid] = o;
  }
}

extern "C" void kernel_launch(void* const* d_in, const int* in_sizes, int n_in,
                              void* d_out, int out_size, void* d_ws, size_t ws_size,
                              hipStream_t stream) {
  const float* x  = (const float*)d_in[0];
  const float* W1 = (const float*)d_in[1];
  const float* W2 = (const float*)d_in[2];
  float* out = (float*)d_out;

  char* ws = (char*)d_ws;
  const size_t nX = (size_t)NBATCH * EMB * SEQ;  // 8,388,608

  size_t off = 0;
  u16* xb   = (u16*)(ws + off); off += nX * 2;                          // 16 MB
  u16* Fcat = (u16*)(ws + off); off += (size_t)NBATCH * SEQ * 1024 * 2; // 32 MB
  const size_t offOverlay = off;                                        // fitb overlays xbT
  u16* xbT  = (u16*)(ws + off); off += nX * 2;                          // 16 MB (dead after D1)
  u16* Wcat = (u16*)(ws + off); off += (size_t)1024 * 512 * 2;          // 1 MB  (dead after D1)
  u16* F2n  = (u16*)(ws + off); off += nX * 2;                          // 16 MB (dead after D2)
  u16* Sd   = (u16*)(ws + off); off += (size_t)NBATCH * 8 * 256 * 256 * 2;  // 8 MB
  u16* Gc   = (u16*)(ws + off); off += (size_t)NBATCH * 8 * EMB * EMB * 2;  // 32 MB
  u16* Gp   = (u16*)(ws + off); off += (size_t)NBATCH * 7 * EMB * EMB * 2;  // 28 MB
  u16* fitb = (u16*)(ws + offOverlay);                                  // 16 MB (over xbT)
  // total: ~149 MiB

  // prep
  prep_x_kernel<<<dim3(SEQ / 64, EMB / 64, NBATCH), 256, 0, stream>>>(x, xb, xbT);
  prep_w_kernel<<<dim3(16, 16, 2), dim3(32, 8), 0, stream>>>(W1, W2, Wcat);

  // D1: Fcat + F2n (share inputs xbT, Wcat)
  k_gemm<0><<<dim3(48, 1, NBATCH), 512, 0, stream>>>(
      xbT, Wcat, nullptr, nullptr, Fcat, F2n);

  // D2: Sd (masked diag Gram, from Fcat) + Gc (xb . F2n^T per chunk)
  k_gemm<1><<<dim3(40, 1, NBATCH), 512, 0, stream>>>(
      Fcat, xb, F2n, nullptr, Sd, Gc);

  // D3: prefix-sum chunks -> Gp
  k_prefix<<<dim3(128, 1, NBATCH), 256, 0, stream>>>(Gc, Gp);

  // D4: fitfused -> fitb (bf16), single continuous 12-tile pipe
  k_gemm<2><<<dim3(16, 1, NBATCH), 512, 0, stream>>>(
      Gp, Fcat, xb, Sd, fitb, nullptr);

  // D5: finalize
  finalize_kernel<<<NBATCH * EMB, 256, 0, stream>>>(xb, fitb, out);
}

// Round 8
// 133.412 us; speedup vs baseline: 1.0505x; 1.0149x over previous
//
#include <hip/hip_runtime.h>
#include <hip/hip_bf16.h>
#include <stdint.h>

// ReplicatorDerivLayer on MI355X — factorized causal pipeline, 256^2 engine v3:
// BK=32, 4-deep LDS buffers (128KB), single barrier per K-tile, vmcnt(8)
// (3-tile prefetch depth), paired-row XOR swizzle (conflict-free b128 reads),
// XCD-aware block-id mapping (xcd = id%8 groups panel-sharing blocks).
//
//  prep_x: x f32 -> xb bf16 [b][e][s] + xbT bf16 [b][s][e]
//  prep_w: Wcat = [W1^T ; W2] bf16 [1024][512]
//  D1: Fcat[s][0:512]=F1T, [512:1024]=F2T;  F2n[r][t] natural layout
//  D2: Sd[b][i] = masked 256^2 diag Gram;  Gc[b][j] = xb_blkj . F2n_blkj^T
//  D3: Gp[b][i-1] = sum_{j<i} Gc[b][j]
//  D4: fitb[e, blk i] = Gp_i.F1T^T (16 tiles) + xb_blk.Sd^T (8 tiles), one pipe
//  D5: avg = sum_s x*fit; out = relu(x*(1+fit-avg))

#define SEQ 2048
#define EMB 512
#define NBATCH 8

typedef unsigned short u16;
typedef __bf16 bf16x8 __attribute__((ext_vector_type(8)));
typedef float f32x4 __attribute__((ext_vector_type(4)));
typedef u16 u16x8 __attribute__((ext_vector_type(8)));

#define AS1 __attribute__((address_space(1)))
#define AS3 __attribute__((address_space(3)))

#define SBAR do { __builtin_amdgcn_sched_barrier(0); __builtin_amdgcn_s_barrier(); \
                  __builtin_amdgcn_sched_barrier(0); } while (0)
#define LGKM0 do { asm volatile("s_waitcnt lgkmcnt(0)" ::: "memory"); \
                   __builtin_amdgcn_sched_barrier(0); } while (0)

__device__ __forceinline__ u16 f2bf(float f) {
  uint32_t u = __builtin_bit_cast(uint32_t, f);
  uint32_t r = u + 0x7FFFu + ((u >> 16) & 1u);
  return (u16)(r >> 16);
}
__device__ __forceinline__ float bf2f(u16 u) {
  return __builtin_bit_cast(float, (uint32_t)u << 16);
}
__device__ __forceinline__ void gld_lds16(const void* g, void* l) {
  __builtin_amdgcn_global_load_lds((AS1 uint32_t*)g, (AS3 uint32_t*)l, 16, 0, 0);
}

// ---------------- prep_x ----------------
__global__ __launch_bounds__(256) void prep_x_kernel(const float* __restrict__ x,
    u16* __restrict__ xb, u16* __restrict__ xbT) {
  __shared__ float tile[64][65];
  const int b = blockIdx.z;
  const int s0 = blockIdx.x * 64, e0 = blockIdx.y * 64;
  const float* xin = x + (size_t)b * EMB * SEQ;
  const int tid = threadIdx.x;
  #pragma unroll
  for (int it = 0; it < 4; ++it) {
    int idx = it * 256 + tid;
    int r = idx >> 4, c4 = idx & 15;
    float4 v = *(const float4*)(xin + (size_t)(e0 + r) * SEQ + s0 + c4 * 4);
    tile[r][c4 * 4 + 0] = v.x; tile[r][c4 * 4 + 1] = v.y;
    tile[r][c4 * 4 + 2] = v.z; tile[r][c4 * 4 + 3] = v.w;
  }
  __syncthreads();
  u16* ob = xb + (size_t)b * EMB * SEQ;
  #pragma unroll
  for (int it = 0; it < 2; ++it) {
    int idx = it * 256 + tid; int r = idx >> 3, c8 = idx & 7;
    u16x8 o;
    #pragma unroll
    for (int q = 0; q < 8; ++q) o[q] = f2bf(tile[r][c8 * 8 + q]);
    *(u16x8*)(ob + (size_t)(e0 + r) * SEQ + s0 + c8 * 8) = o;
  }
  u16* obT = xbT + (size_t)b * SEQ * EMB;
  #pragma unroll
  for (int it = 0; it < 2; ++it) {
    int idx = it * 256 + tid; int r = idx >> 3, c8 = idx & 7;
    u16x8 o;
    #pragma unroll
    for (int q = 0; q < 8; ++q) o[q] = f2bf(tile[c8 * 8 + q][r]);
    *(u16x8*)(obT + (size_t)(s0 + r) * EMB + e0 + c8 * 8) = o;
  }
}

// ---------------- prep_w: Wcat = [W1^T ; W2] ----------------
__global__ __launch_bounds__(256) void prep_w_kernel(const float* __restrict__ W1,
    const float* __restrict__ W2, u16* __restrict__ Wcat) {
  __shared__ float tile[32][33];
  const int c0 = blockIdx.x * 32, r0 = blockIdx.y * 32;
  const int tx = threadIdx.x, ty = threadIdx.y;  // (32, 8)
  if (blockIdx.z == 0) {
    #pragma unroll
    for (int i = 0; i < 32; i += 8)
      tile[ty + i][tx] = W1[(size_t)(r0 + ty + i) * EMB + c0 + tx];
    __syncthreads();
    #pragma unroll
    for (int i = 0; i < 32; i += 8)
      Wcat[(size_t)(c0 + ty + i) * EMB + r0 + tx] = f2bf(tile[tx][ty + i]);
  } else {
    u16* W2b = Wcat + (size_t)512 * 512;
    #pragma unroll
    for (int i = 0; i < 32; i += 8)
      W2b[(size_t)(r0 + ty + i) * EMB + c0 + tx] =
          f2bf(W2[(size_t)(r0 + ty + i) * EMB + c0 + tx]);
  }
}

// ---------------- 256x256 engine v3: BK=32, 4-deep, 1 barrier/K-tile ----------------
struct Smem {
  __align__(16) u16 A[4][8192];   // 4 bufs x 256 rows x 32 cols bf16 (16KB)
  __align__(16) u16 B[4][8192];
};

// par(t, ab, g, ld, k): operand source for K-tile t (32 cols), ab: 0=A, 1=B.
template<typename PAR>
__device__ __forceinline__ void gemm_pipe(PAR par, int nk, Smem& sm, f32x4 (&acc)[8][4]) {
  const int tid = threadIdx.x, lane = tid & 63, wave = tid >> 6;
  const int wr = wave >> 2, wc = wave & 3;
  const int ar = lane & 15, asel = lane >> 4;

  // LDS layout per buf: 128 lines of 128B; line L holds rows 2L,2L+1 (4 chunks each);
  // chunk position within line = c' ^ (L&7), c' = (row&1)*4 + colchunk.
  // -> frag reads (16 lanes, rows r..r+15, same colchunk) are bank-conflict-free.
  auto stage = [&](int t) {
    const u16 *ga, *gb; int lda, ldb, ka, kb;
    par(t, 0, ga, lda, ka);
    par(t, 1, gb, ldb, kb);
    u16* LA = sm.A[t & 3];
    u16* LB = sm.B[t & 3];
    #pragma unroll
    for (int p = 0; p < 2; ++p) {
      int idx = p * 512 + tid;
      int line = idx >> 3, cp = (idx & 7) ^ (line & 7);
      int row = line * 2 + (cp >> 2), cc = cp & 3;
      gld_lds16(ga + (size_t)row * lda + ka + cc * 8, LA + (size_t)(p * 512 + wave * 64) * 8);
      gld_lds16(gb + (size_t)row * ldb + kb + cc * 8, LB + (size_t)(p * 512 + wave * 64) * 8);
    }
  };
  auto ldfrag = [&](const u16* base, int rloc) -> bf16x8 {
    int line = rloc >> 1;
    int ch = line * 8 + ((((rloc & 1) << 2) | asel) ^ (line & 7));
    return *reinterpret_cast<const bf16x8*>(base + (size_t)ch * 8);
  };

  // prologue: 3 tiles in flight (12 loads/thread); wait oldest 4 -> tile0 ready
  stage(0); stage(1); stage(2);
  asm volatile("s_waitcnt vmcnt(8)" ::: "memory");
  SBAR;

  for (int t = 0; t < nk; ++t) {
    const u16* A = sm.A[t & 3];
    const u16* B = sm.B[t & 3];
    bf16x8 af[8], bf[4];
    #pragma unroll
    for (int m = 0; m < 8; ++m) af[m] = ldfrag(A, wr * 128 + m * 16 + ar);
    #pragma unroll
    for (int n = 0; n < 4; ++n) bf[n] = ldfrag(B, wc * 64 + n * 16 + ar);
    if (t + 3 < nk) stage(t + 3);   // targets buf[(t-1)&3]: reads drained pre-barrier
    LGKM0;
    __builtin_amdgcn_s_setprio(1);
    #pragma unroll
    for (int m = 0; m < 8; ++m)
      #pragma unroll
      for (int n = 0; n < 4; ++n)
        acc[m][n] = __builtin_amdgcn_mfma_f32_16x16x32_bf16(af[m], bf[n], acc[m][n], 0, 0, 0);
    __builtin_amdgcn_s_setprio(0);
    if (t + 1 < nk) {   // certify tile t+1 arrived; keep newer stages in flight
      if (t + 3 < nk)      { asm volatile("s_waitcnt vmcnt(8)" ::: "memory"); }
      else if (t + 2 < nk) { asm volatile("s_waitcnt vmcnt(4)" ::: "memory"); }
      else                 { asm volatile("s_waitcnt vmcnt(0)" ::: "memory"); }
    }
    SBAR;
  }
}

// ---------------- GEMM kernels ----------------
// xcd = blockIdx.x & 7 groups panel-sharing blocks on one XCD (gridDim.x % 8 == 0).
// MODE 0 grid (48,1,8): g<4 -> Fcat (m=x, n=g); g in {4,5} -> F2n (m2=g-4, n2=x)
// MODE 1 grid (40,1,8): g==0 -> Sd[i=x] masked diag; g>=1 -> Gc (j=x, sub=g-1)
// MODE 2 grid (16,1,8): fitb (i=x s-block, m=g e-half), 24-tile fused pipe
template<int MODE>
__global__ __launch_bounds__(512, 2) void k_gemm(
    const u16* __restrict__ X1, const u16* __restrict__ X2,
    const u16* __restrict__ X3, const u16* __restrict__ X4,
    u16* __restrict__ O16, u16* __restrict__ O16b) {
  __shared__ Smem sm;
  const int tid  = threadIdx.x;
  const int lane = tid & 63;
  const int wave = tid >> 6;
  const int wr = wave >> 2;
  const int wc = wave & 3;
  const int bz = blockIdx.z;
  const int x = blockIdx.x & 7, g = blockIdx.x >> 3;

  f32x4 acc[8][4];
  #pragma unroll
  for (int i = 0; i < 8; ++i)
    #pragma unroll
    for (int j = 0; j < 4; ++j) acc[i][j] = (f32x4){0.f, 0.f, 0.f, 0.f};

  const int r0 = (lane >> 4) * 4;
  const int cn = lane & 15;

  if (MODE == 0) {
    const u16 *Ap, *Bp;
    if (g < 4) {      // Fcat: m = x, n = g  (same-A blocks share xcd=m? no: same m -> same x ✓)
      Ap = X1 + (size_t)bz * SEQ * EMB + (size_t)(x * 256) * 512;
      Bp = X2 + (size_t)(g * 256) * 512;
    } else {          // F2n: m2 = g-4, n2 = x (pairs sharing B-panel share xcd)
      Ap = X2 + (size_t)512 * 512 + (size_t)((g - 4) * 256) * 512;
      Bp = X1 + (size_t)bz * SEQ * EMB + (size_t)(x * 256) * 512;
    }
    auto par = [&](int t, int ab, const u16*& gp, int& ld, int& k) {
      gp = ab ? Bp : Ap; ld = 512; k = t * 32;
    };
    gemm_pipe(par, 16, sm, acc);
    if (g < 4) {
      u16* C = O16 + (size_t)bz * SEQ * 1024;
      #pragma unroll
      for (int mm = 0; mm < 8; ++mm)
        #pragma unroll
        for (int nn = 0; nn < 4; ++nn)
          #pragma unroll
          for (int r = 0; r < 4; ++r) {
            int lr = wr * 128 + mm * 16 + r0 + r, lc = wc * 64 + nn * 16 + cn;
            C[(size_t)(x * 256 + lr) * 1024 + g * 256 + lc] = f2bf(acc[mm][nn][r]);
          }
    } else {
      u16* C = O16b + (size_t)bz * EMB * SEQ;
      #pragma unroll
      for (int mm = 0; mm < 8; ++mm)
        #pragma unroll
        for (int nn = 0; nn < 4; ++nn)
          #pragma unroll
          for (int r = 0; r < 4; ++r) {
            int lr = wr * 128 + mm * 16 + r0 + r, lc = wc * 64 + nn * 16 + cn;
            C[(size_t)((g - 4) * 256 + lr) * SEQ + x * 256 + lc] = f2bf(acc[mm][nn][r]);
          }
    }
  } else if (MODE == 1) {
    if (g == 0) {     // Sd[i = x], masked diag Gram, K = 512
      const u16* Fb = X1 + (size_t)bz * SEQ * 1024;
      const u16* Ap = Fb + (size_t)(x * 256) * 1024;
      const u16* Bp = Fb + 512 + (size_t)(x * 256) * 1024;
      auto par = [&](int t, int ab, const u16*& gp, int& ld, int& k) {
        gp = ab ? Bp : Ap; ld = 1024; k = t * 32;
      };
      gemm_pipe(par, 16, sm, acc);
      u16* C = O16 + (size_t)(bz * 8 + x) * 256 * 256;
      #pragma unroll
      for (int mm = 0; mm < 8; ++mm)
        #pragma unroll
        for (int nn = 0; nn < 4; ++nn)
          #pragma unroll
          for (int r = 0; r < 4; ++r) {
            int lr = wr * 128 + mm * 16 + r0 + r, lc = wc * 64 + nn * 16 + cn;
            float v = (lc > lr) ? 0.f : acc[mm][nn][r];  // keep t <= s
            C[(size_t)lr * 256 + lc] = f2bf(v);
          }
    } else {          // Gc: j = x, sub = g-1: m = sub>>1, n = sub&1, K = 256
      const int m = (g - 1) >> 1, n = (g - 1) & 1;
      const u16* Ap = X2 + (size_t)bz * EMB * SEQ + (size_t)(m * 256) * SEQ + x * 256;
      const u16* Bp = X3 + (size_t)bz * EMB * SEQ + (size_t)(n * 256) * SEQ + x * 256;
      auto par = [&](int t, int ab, const u16*& gp, int& ld, int& k) {
        gp = ab ? Bp : Ap; ld = SEQ; k = t * 32;
      };
      gemm_pipe(par, 8, sm, acc);
      u16* C = O16b + (size_t)(bz * 8 + x) * EMB * EMB;
      #pragma unroll
      for (int mm = 0; mm < 8; ++mm)
        #pragma unroll
        for (int nn = 0; nn < 4; ++nn)
          #pragma unroll
          for (int r = 0; r < 4; ++r) {
            int lr = wr * 128 + mm * 16 + r0 + r, lc = wc * 64 + nn * 16 + cn;
            C[(size_t)(m * 256 + lr) * EMB + n * 256 + lc] = f2bf(acc[mm][nn][r]);
          }
    }
  } else {
    // fitfused: i = x (s-block), m = g (e-half); tiles 0-15: Gp_i.F1T^T; 16-23: xb.Sd^T
    const int i = x, m = g;
    const u16* Agp = (i > 0) ? X1 + (size_t)(bz * 7 + i - 1) * EMB * EMB + (size_t)(m * 256) * 512
                             : X1;
    const u16* Bf1 = X2 + (size_t)bz * SEQ * 1024 + (size_t)(i * 256) * 1024;
    const u16* Axb = X3 + (size_t)bz * EMB * SEQ + (size_t)(m * 256) * SEQ;
    const u16* Bsd = X4 + (size_t)(bz * 8 + i) * 256 * 256;
    auto par = [&](int t, int ab, const u16*& gp, int& ld, int& k) {
      int tt = (i > 0) ? t : t + 16;
      if (tt < 16) {
        if (!ab) { gp = Agp; ld = 512;  k = tt * 32; }
        else     { gp = Bf1; ld = 1024; k = tt * 32; }
      } else {
        int u = tt - 16;
        if (!ab) { gp = Axb; ld = SEQ; k = i * 256 + u * 32; }
        else     { gp = Bsd; ld = 256; k = u * 32; }
      }
    };
    gemm_pipe(par, (i > 0) ? 24 : 8, sm, acc);
    u16* C = O16 + (size_t)bz * EMB * SEQ;
    #pragma unroll
    for (int mm = 0; mm < 8; ++mm)
      #pragma unroll
      for (int nn = 0; nn < 4; ++nn)
        #pragma unroll
        for (int r = 0; r < 4; ++r) {
          int lr = wr * 128 + mm * 16 + r0 + r, lc = wc * 64 + nn * 16 + cn;
          C[(size_t)(m * 256 + lr) * SEQ + i * 256 + lc] = f2bf(acc[mm][nn][r]);
        }
  }
}

// ---------------- prefix over chunks: Gp[b][i-1] = sum_{j<i} Gc[b][j] ----------------
__global__ __launch_bounds__(256) void k_prefix(const u16* __restrict__ Gc,
                                                u16* __restrict__ Gp) {
  const int b = blockIdx.z;
  const size_t base = ((size_t)blockIdx.x * 256 + threadIdx.x) * 8;
  float run[8] = {0.f, 0.f, 0.f, 0.f, 0.f, 0.f, 0.f, 0.f};
  #pragma unroll
  for (int j = 0; j < 7; ++j) {
    u16x8 v = *(const u16x8*)(Gc + (size_t)(b * 8 + j) * EMB * EMB + base);
    u16x8 o;
    #pragma unroll
    for (int q = 0; q < 8; ++q) { run[q] += bf2f(v[q]); o[q] = f2bf(run[q]); }
    *(u16x8*)(Gp + (size_t)(b * 7 + j) * EMB * EMB + base) = o;
  }
}

// ---------------- finalize (fit in bf16) ----------------
__global__ __launch_bounds__(256) void finalize_kernel(const u16* __restrict__ xb,
    const u16* __restrict__ fitb, float* __restrict__ out) {
  const size_t row = blockIdx.x;  // b*EMB + e
  const u16* xr = xb + row * SEQ;
  const u16* fr = fitb + row * SEQ;
  float* orow = out + row * SEQ;
  const int tid = threadIdx.x;

  float xv[2][4], fv[2][4];
  float part = 0.f;
  #pragma unroll
  for (int i = 0; i < 2; ++i) {
    const int s0 = i * 1024 + tid * 4;
    ushort4 xu = *reinterpret_cast<const ushort4*>(xr + s0);
    ushort4 fu = *reinterpret_cast<const ushort4*>(fr + s0);
    xv[i][0] = bf2f(xu.x); xv[i][1] = bf2f(xu.y); xv[i][2] = bf2f(xu.z); xv[i][3] = bf2f(xu.w);
    fv[i][0] = bf2f(fu.x); fv[i][1] = bf2f(fu.y); fv[i][2] = bf2f(fu.z); fv[i][3] = bf2f(fu.w);
    part += xv[i][0] * fv[i][0] + xv[i][1] * fv[i][1] + xv[i][2] * fv[i][2] + xv[i][3] * fv[i][3];
  }
  #pragma unroll
  for (int off = 1; off < 64; off <<= 1) part += __shfl_xor(part, off);
  __shared__ float wsum[4];
  const int wave = tid >> 6, lane = tid & 63;
  if (lane == 0) wsum[wave] = part;
  __syncthreads();
  const float avg = wsum[0] + wsum[1] + wsum[2] + wsum[3];

  #pragma unroll
  for (int i = 0; i < 2; ++i) {
    float4 o;
    o.x = xv[i][0] * (1.f + fv[i][0] - avg); o.x = o.x > 0.f ? o.x : 0.f;
    o.y = xv[i][1] * (1.f + fv[i][1] - avg); o.y = o.y > 0.f ? o.y : 0.f;
    o.z = xv[i][2] * (1.f + fv[i][2] - avg); o.z = o.z > 0.f ? o.z : 0.f;
    o.w = xv[i][3] * (1.f + fv[i][3] - avg); o.w = o.w > 0.f ? o.w : 0.f;
    reinterpret_cast<float4*>(orow)[i * 256 + tid] = o;
  }
}

extern "C" void kernel_launch(void* const* d_in, const int* in_sizes, int n_in,
                              void* d_out, int out_size, void* d_ws, size_t ws_size,
                              hipStream_t stream) {
  const float* x  = (const float*)d_in[0];
  const float* W1 = (const float*)d_in[1];
  const float* W2 = (const float*)d_in[2];
  float* out = (float*)d_out;

  char* ws = (char*)d_ws;
  const size_t nX = (size_t)NBATCH * EMB * SEQ;  // 8,388,608

  size_t off = 0;
  u16* xb   = (u16*)(ws + off); off += nX * 2;                          // 16 MB
  u16* Fcat = (u16*)(ws + off); off += (size_t)NBATCH * SEQ * 1024 * 2; // 32 MB
  const size_t offOverlay = off;                                        // fitb overlays xbT
  u16* xbT  = (u16*)(ws + off); off += nX * 2;                          // 16 MB (dead after D1)
  u16* Wcat = (u16*)(ws + off); off += (size_t)1024 * 512 * 2;          // 1 MB  (dead after D1)
  u16* F2n  = (u16*)(ws + off); off += nX * 2;                          // 16 MB (dead after D2)
  u16* Sd   = (u16*)(ws + off); off += (size_t)NBATCH * 8 * 256 * 256 * 2;  // 8 MB
  u16* Gc   = (u16*)(ws + off); off += (size_t)NBATCH * 8 * EMB * EMB * 2;  // 32 MB
  u16* Gp   = (u16*)(ws + off); off += (size_t)NBATCH * 7 * EMB * EMB * 2;  // 28 MB
  u16* fitb = (u16*)(ws + offOverlay);                                  // 16 MB (over xbT)
  // total: ~149 MiB

  // prep
  prep_x_kernel<<<dim3(SEQ / 64, EMB / 64, NBATCH), 256, 0, stream>>>(x, xb, xbT);
  prep_w_kernel<<<dim3(16, 16, 2), dim3(32, 8), 0, stream>>>(W1, W2, Wcat);

  // D1: Fcat + F2n
  k_gemm<0><<<dim3(48, 1, NBATCH), 512, 0, stream>>>(
      xbT, Wcat, nullptr, nullptr, Fcat, F2n);

  // D2: Sd (masked diag Gram) + Gc (xb . F2n^T per chunk)
  k_gemm<1><<<dim3(40, 1, NBATCH), 512, 0, stream>>>(
      Fcat, xb, F2n, nullptr, Sd, Gc);

  // D3: prefix-sum chunks -> Gp
  k_prefix<<<dim3(128, 1, NBATCH), 256, 0, stream>>>(Gc, Gp);

  // D4: fitfused -> fitb (bf16), single 24-tile pipe
  k_gemm<2><<<dim3(16, 1, NBATCH), 512, 0, stream>>>(
      Gp, Fcat, xb, Sd, fitb, nullptr);

  // D5: finalize
  finalize_kernel<<<NBATCH * EMB, 256, 0, stream>>>(xb, fitb, out);
}